// Round 14
// baseline (231.402 us; speedup 1.0000x reference)
//
#include <hip/hip_runtime.h>
#include <hip/hip_bf16.h>

#define NN 4096
#define FIN 128
#define FOUT 64
#define NH 8
#define KS 4          // K splits (1024 keys per block)
#define QT 32         // Q rows per attn block

typedef float f32x4 __attribute__((ext_vector_type(4)));
typedef __bf16 bf16x8 __attribute__((ext_vector_type(8)));
typedef unsigned long long u64;

// ---------------- K0: fused prep: per-block redundant Wc + scores/EF/C12/skipm + Vt.
// 256 blocks x 16 rows. LDS 48.6 KB, no role mixing (R13 lesson).
__global__ __launch_bounds__(256) void prepsv_kernel(
    const float* __restrict__ x, const float* __restrict__ proj,
    const float* __restrict__ score_src, const float* __restrict__ score_dst,
    const float* __restrict__ skip_w,
    float* __restrict__ skipm, unsigned* __restrict__ EF, float2* __restrict__ C12,
    __hip_bfloat16* __restrict__ Vt_) {
    __shared__ float xs[16][FIN + 5];              // 8.5 KB
    __shared__ __align__(16) char ubuf[40960];     // wcs fp32[128][80]  ->  xbs+pTs
    float* wcs = (float*)ubuf;
    const int tid = threadIdx.x;
    const int n0 = blockIdx.x * 16;

    // stage x tile (16 x 128 fp32)
    const float4* xsrc = (const float4*)(x + (size_t)n0 * FIN);
    for (int i = tid; i < 16 * FIN / 4; i += 256) {
        int r = i >> 5, c4 = i & 31;
        *(float4*)&xs[r][c4 * 4] = xsrc[i];
    }
    // Wc score cols 0..15 = proj[h] @ score_{src,dst}[h]
    for (int t = tid; t < 2048; t += 256) {
        int i = t >> 4, c = t & 15, h = c & 7;
        const float* wv = (c < 8 ? score_src : score_dst) + h * FOUT;
        const float* p = proj + (size_t)h * FIN * FOUT + (size_t)i * FOUT;
        float v = 0.f;
#pragma unroll 8
        for (int f = 0; f < FOUT; ++f) v += p[f] * wv[f];
        wcs[i * 80 + c] = v;
    }
    // Wc skip cols 16..79 = head-folded skip_w / 8
    for (int t = tid; t < 8192; t += 256) {
        int i = t >> 6, f = t & 63;
        float v = 0.f;
#pragma unroll
        for (int h = 0; h < NH; ++h) v += skip_w[(size_t)(h * FOUT + f) * FIN + i];
        wcs[i * 80 + 16 + f] = 0.125f * v;
    }
    __syncthreads();

    // scores + skipm: 16 groups x 16 rows (R12 scores structure)
    {
        const int r = tid & 15, g = tid >> 4;
        float acc[4];
        float sa = 0.f;
#pragma unroll
        for (int j = 0; j < 4; ++j) acc[j] = 0.f;
#pragma unroll 4
        for (int i = 0; i < FIN; ++i) {
            float xv = xs[r][i];
            const float* wr = &wcs[i * 80];
            float4 p = *(float4*)(wr + 16 + g * 4);
            float qv = wr[g];
            acc[0] += xv * p.x; acc[1] += xv * p.y; acc[2] += xv * p.z; acc[3] += xv * p.w;
            sa += xv * qv;
        }
        int n = n0 + r;
#pragma unroll
        for (int j = 0; j < 4; ++j) skipm[(size_t)n * FOUT + g * 4 + j] = acc[j];
        if (g < 8) {
            C12[g * NN + n] = make_float2(expf(sa), expf(0.2f * sa));
        } else {
            __hip_bfloat16 e0 = __float2bfloat16(expf(sa));
            __hip_bfloat16 f0 = __float2bfloat16(expf(0.2f * sa));
            EF[(g - 8) * NN + n] = ((unsigned)*(unsigned short*)&f0 << 16) | (unsigned)*(unsigned short*)&e0;
        }
    }
    __syncthreads();   // wcs reads done; ubuf reusable

    // x -> bf16 into LDS + pT staging + per-head Vt MFMA
    __bf16 (*xbs)[136] = (__bf16 (*)[136])ubuf;                 // 4.4 KB
    __bf16 (*pTs)[136] = (__bf16 (*)[136])(ubuf + 4352);        // 17.4 KB
    {
        int row = tid >> 4, col0 = (tid & 15) * 8;
        const float* src = &xs[row][col0];
        bf16x8 b0;
#pragma unroll
        for (int j = 0; j < 8; ++j) b0[j] = (__bf16)src[j];
        *(bf16x8*)&xbs[row][col0] = b0;
    }
    for (int idx = tid; idx < FIN * FOUT; idx += 256) {
        int i = idx >> 6, f = idx & 63;
        pTs[f][i] = (__bf16)proj[idx];                           // head 0
    }
    __syncthreads();

    const int lane = tid & 63, q = lane >> 4, li = lane & 15, w = tid >> 6;
    __bf16* Vt = (__bf16*)Vt_;
#pragma unroll 1
    for (int h = 0; h < NH; ++h) {
        f32x4 va = (f32x4){0.f, 0.f, 0.f, 0.f};
#pragma unroll
        for (int kt = 0; kt < 4; ++kt) {
            bf16x8 bfrag = *(const bf16x8*)&xbs[li][kt * 32 + q * 8];
            bf16x8 afrag = *(const bf16x8*)&pTs[w * 16 + li][kt * 32 + q * 8];
            va = __builtin_amdgcn_mfma_f32_16x16x32_bf16(afrag, bfrag, va, 0, 0, 0);
        }
#pragma unroll
        for (int reg = 0; reg < 4; ++reg)
            Vt[((size_t)h * FOUT + w * 16 + q * 4 + reg) * NN + n0 + li] = (__bf16)va[reg];
        __syncthreads();
        if (h < 7) {
            const float* ph = proj + (size_t)(h + 1) * FIN * FOUT;
            for (int idx = tid; idx < FIN * FOUT; idx += 256) {
                int i = idx >> 6, f = idx & 63;
                pTs[f][i] = (__bf16)ph[idx];
            }
            __syncthreads();
        }
    }
}

// ---------------- K1: attention, all-8-heads blocks, in-block mask ballot,
// per-wave LDS-DMA double buffer (R12 K-loop unchanged per-wave).
// grid = 128 qt x 4 ks = 512 blocks x 512 thr; LDS 68.4 KB -> 2 blocks/CU (= grid/CU).
__attribute__((amdgpu_waves_per_eu(4)))
__global__ __launch_bounds__(512) void attn_kernel(
    const float* __restrict__ topo, const __hip_bfloat16* __restrict__ Vt_,
    const unsigned* __restrict__ EFg, const float2* __restrict__ C12g,
    __hip_bfloat16* __restrict__ accP, float* __restrict__ rsP) {
    __shared__ u64 maskS[QT][17];         // 4.4 KB
    __shared__ char vA[8][4096];          // 32 KB
    __shared__ char vB[8][4096];          // 32 KB
    const int tid = threadIdx.x;
    const int w = tid >> 6;               // wave = head 0..7
    const int lane = tid & 63, q = lane >> 4, li = lane & 15;
    const int qt = blockIdx.x >> 2, ks = blockIdx.x & 3;
    const int row0 = qt * QT;
    const int kb0 = ks * 1024;

    const int r_ = lane >> 2;
    const int sg = ((lane & 3) - (r_ >> 1)) & 3;
    const size_t laneoff = (size_t)r_ * NN + sg * 8;            // bf16 units
    const int rdoff = li * 64 + ((q + (li >> 1)) & 3) * 16;     // bytes

    const __bf16* vb = (const __bf16*)Vt_ + (size_t)w * (FOUT * NN) + kb0;
    const unsigned* efb = EFg + (size_t)w * NN + kb0;

#define DMA_TILE(DST, KT) do {                                                     \
    _Pragma("unroll")                                                              \
    for (int c = 0; c < 4; ++c) {                                                  \
        const __bf16* g_ = vb + (size_t)c * (16 * NN) + (KT) * 32 + laneoff;       \
        __builtin_amdgcn_global_load_lds(                                          \
            (const __attribute__((address_space(1))) void*)g_,                     \
            (__attribute__((address_space(3))) void*)&DST[w][c * 1024], 16, 0, 0); \
    }                                                                              \
} while (0)

    DMA_TILE(vA, 0);
    {   // mask ballot: 512 words; wave w owns words w*64..w*64+63 (row = wd>>4, col = wd&15)
        const float* tpb = topo + (size_t)row0 * NN + kb0;
#pragma unroll 1
        for (int it = 0; it < 64; it += 4) {
            int w0 = w * 64 + it;
            float t0 = tpb[(size_t)((w0 + 0) >> 4) * NN + ((w0 + 0) & 15) * 64 + lane];
            float t1 = tpb[(size_t)((w0 + 1) >> 4) * NN + ((w0 + 1) & 15) * 64 + lane];
            float t2 = tpb[(size_t)((w0 + 2) >> 4) * NN + ((w0 + 2) & 15) * 64 + lane];
            float t3 = tpb[(size_t)((w0 + 3) >> 4) * NN + ((w0 + 3) & 15) * 64 + lane];
            u64 b0 = __ballot(t0 > -0.5e9f);
            u64 b1 = __ballot(t1 > -0.5e9f);
            u64 b2 = __ballot(t2 > -0.5e9f);
            u64 b3 = __ballot(t3 > -0.5e9f);
            if (lane == 0) {
                maskS[(w0 + 0) >> 4][(w0 + 0) & 15] = b0;
                maskS[(w0 + 1) >> 4][(w0 + 1) & 15] = b1;
                maskS[(w0 + 2) >> 4][(w0 + 2) & 15] = b2;
                maskS[(w0 + 3) >> 4][(w0 + 3) & 15] = b3;
            }
        }
    }
    __syncthreads();                      // LDS writes visible; DMA(0) retired (in-order)

    float C1[2], C2[2];
#pragma unroll
    for (int rt = 0; rt < 2; ++rt) {
        float2 c = C12g[(size_t)w * NN + row0 + rt * 16 + li];
        C1[rt] = c.x; C2[rt] = c.y;
    }
    bf16x8 ones;
#pragma unroll
    for (int j = 0; j < 8; ++j) ones[j] = (__bf16)1.0f;

    f32x4 acc[2][4];
    f32x4 rsacc[2];
#pragma unroll
    for (int rt = 0; rt < 2; ++rt) {
#pragma unroll
        for (int n = 0; n < 4; ++n) acc[rt][n] = (f32x4){0.f, 0.f, 0.f, 0.f};
        rsacc[rt] = (f32x4){0.f, 0.f, 0.f, 0.f};
    }

#define CHUNK_BODY(SRC, DSTN, KT) do {                                                        \
    const unsigned* ep_ = efb + (KT) * 32 + q * 8;                                            \
    uint4 ea_ = *(const uint4*)ep_;                                                           \
    uint4 eb_ = *(const uint4*)(ep_ + 4);                                                     \
    asm volatile("" ::: "memory");             /* pin EF loads before the DMA */              \
    DMA_TILE(DSTN, ((KT) + 1) & 31);                                                          \
    asm volatile("s_waitcnt vmcnt(4)" ::: "memory");                                          \
    bf16x8 vf_[4];                                                                            \
    _Pragma("unroll")                                                                         \
    for (int n = 0; n < 4; ++n)                                                               \
        vf_[n] = *(const bf16x8*)&SRC[w][n * 1024 + rdoff];                                   \
    unsigned ew_[8] = {ea_.x, ea_.y, ea_.z, ea_.w, eb_.x, eb_.y, eb_.z, eb_.w};               \
    _Pragma("unroll")                                                                         \
    for (int rt = 0; rt < 2; ++rt) {                                                          \
        u64 mw_ = maskS[rt * 16 + li][(KT) >> 1];                                             \
        unsigned mm_ = (unsigned)(mw_ >> (((KT) & 1) * 32 + q * 8)) & 0xffu;                  \
        bf16x8 pf_;                                                                           \
        _Pragma("unroll")                                                                     \
        for (int j = 0; j < 8; ++j) {                                                         \
            unsigned e_ = ew_[j];                                                             \
            float E_ = __uint_as_float(e_ << 16);                                             \
            float F_ = __uint_as_float(e_ & 0xffff0000u);                                     \
            float pv_ = fmaxf(C1[rt] * E_, C2[rt] * F_);                                      \
            pv_ = ((mm_ >> j) & 1u) ? pv_ : 0.f;                                              \
            pf_[j] = (__bf16)pv_;                                                             \
        }                                                                                     \
        rsacc[rt] = __builtin_amdgcn_mfma_f32_16x16x32_bf16(pf_, ones, rsacc[rt], 0, 0, 0);   \
        _Pragma("unroll")                                                                     \
        for (int n = 0; n < 4; ++n)                                                           \
            acc[rt][n] = __builtin_amdgcn_mfma_f32_16x16x32_bf16(pf_, vf_[n], acc[rt][n],     \
                                                                 0, 0, 0);                    \
    }                                                                                         \
} while (0)

#pragma unroll 1
    for (int kt = 0; kt < 32; kt += 2) {
        CHUNK_BODY(vA, vB, kt);
        CHUNK_BODY(vB, vA, kt + 1);
    }
#undef CHUNK_BODY
#undef DMA_TILE

    // epilogue: unnormalized bf16 partials + fp32 row sums (C-layout: row = q*4+reg)
#pragma unroll
    for (int rt = 0; rt < 2; ++rt) {
        if (li == 0) {
#pragma unroll
            for (int reg = 0; reg < 4; ++reg)
                rsP[(size_t)(ks * NH + w) * NN + row0 + rt * 16 + q * 4 + reg] = rsacc[rt][reg];
        }
        __hip_bfloat16* ap = accP + ((size_t)(ks * NH + w) * NN + row0 + rt * 16) * 64;
#pragma unroll
        for (int n = 0; n < 4; ++n)
#pragma unroll
            for (int reg = 0; reg < 4; ++reg)
                ap[(q * 4 + reg) * 64 + n * 16 + li] = __float2bfloat16(acc[rt][n][reg]);
    }
}

// ---------------- K2: combine k-split partials + mean heads + skip + LeakyReLU
__global__ __launch_bounds__(256) void combine_kernel(
    const __hip_bfloat16* __restrict__ accP, const float* __restrict__ rsP,
    float* __restrict__ out) {
    int idx = blockIdx.x * 256 + threadIdx.x;      // 262144
    int row = idx >> 6, f = idx & 63;
    float s = 0.f;
#pragma unroll 1
    for (int h = 0; h < NH; ++h) {
        float a = 0.f, r = 0.f;
#pragma unroll
        for (int k = 0; k < KS; ++k) {
            a += __bfloat162float(accP[((size_t)(k * NH + h) * NN + row) * 64 + f]);
            r += rsP[(size_t)(k * NH + h) * NN + row];
        }
        s += a / r;
    }
    float v = s * 0.125f + out[idx];               // out currently holds skipm
    out[idx] = fmaxf(v, 0.2f * v);
}

extern "C" void kernel_launch(void* const* d_in, const int* in_sizes, int n_in,
                              void* d_out, int out_size, void* d_ws, size_t ws_size,
                              hipStream_t stream) {
    (void)in_sizes; (void)n_in; (void)out_size; (void)ws_size;
    const float* x         = (const float*)d_in[0];   // [4096,128]
    const float* topology  = (const float*)d_in[1];   // [4096,4096]
    const float* proj      = (const float*)d_in[2];   // [8,128,64]
    const float* score_src = (const float*)d_in[3];   // [8,64]
    const float* score_dst = (const float*)d_in[4];   // [8,64]
    const float* skip_w    = (const float*)d_in[5];   // [512,128]
    float* out = (float*)d_out;                       // [4096,64]

    char* ws = (char*)d_ws;
    __hip_bfloat16* Vt = (__hip_bfloat16*)ws;                 // 4 MB
    unsigned* EF  = (unsigned*)(ws + 4194304);                // 128 KB
    float2* C12   = (float2*)(ws + 4325376);                  // 256 KB
    float* rsP    = (float*)(ws + 4587520);                   // 512 KB
    __hip_bfloat16* accP = (__hip_bfloat16*)(ws + 5111808);   // 16 MB (end ~21.1 MB)
    float* skipm = out;   // skip GEMM lives in d_out; combine consumes & overwrites

    prepsv_kernel<<<256, 256, 0, stream>>>(x, proj, score_src, score_dst, skip_w,
                                           skipm, EF, C12, Vt);
    attn_kernel<<<512, 512, 0, stream>>>(topology, Vt, EF, C12, accP, rsP);
    combine_kernel<<<1024, 256, 0, stream>>>(accP, rsP, out);
}

// Round 16
// 184.015 us; speedup vs baseline: 1.2575x; 1.2575x over previous
//
#include <hip/hip_runtime.h>
#include <hip/hip_bf16.h>

#define NN 4096
#define FIN 128
#define FOUT 64
#define NH 8
#define KS 4          // K splits (1024 keys per block)
#define QT 32         // Q rows per block

typedef float f32x4 __attribute__((ext_vector_type(4)));
typedef __bf16 bf16x8 __attribute__((ext_vector_type(8)));
typedef unsigned long long u64;

// ---------------- K0: fused mask + Wc (both roles LDS-free -> no occupancy coupling).
// Blocks 0..2047: topology -> bitmask streaming. Blocks 2048..2087: Wc[128][80].
__global__ __launch_bounds__(256) void maskwc_kernel(
    const float* __restrict__ topo, u64* __restrict__ mb,
    const float* __restrict__ proj, const float* __restrict__ score_src,
    const float* __restrict__ score_dst, const float* __restrict__ skip_w,
    float* __restrict__ Wc) {
    const int tid = threadIdx.x;
    if (blockIdx.x < 2048) {               // ---- mask role
        const int w = blockIdx.x * 4 + (tid >> 6);
        const int lane = tid & 63;
        size_t base = (size_t)w * 32;
#pragma unroll 4
        for (int it = 0; it < 32; ++it) {
            size_t u = base + it;
            float t = topo[u * 64 + lane];
            u64 b = __ballot(t > -0.5e9f);
            if (lane == 0) mb[u] = b;
        }
        return;
    }
    // ---- wc role
    int idx = (blockIdx.x - 2048) * 256 + tid;
    if (idx >= FIN * 80) return;
    int i = idx / 80, c = idx % 80;
    float v = 0.f;
    if (c < 16) {
        int h = c & 7;
        const float* w = (c < 8 ? score_src : score_dst) + h * FOUT;
        const float* p = proj + (size_t)h * FIN * FOUT + (size_t)i * FOUT;
        for (int f = 0; f < FOUT; ++f) v += p[f] * w[f];
    } else {
        int f = c - 16;
        for (int h = 0; h < NH; ++h) v += skip_w[(size_t)(h * FOUT + f) * FIN + i];
        v *= 0.125f;
    }
    Wc[i * 80 + c] = v;
}

// ---------------- K1: x@Wc -> skipm (in d_out), EF, C12, xb (R12, unchanged)
__global__ __launch_bounds__(256) void scores_kernel(
    const float* __restrict__ x, const float* __restrict__ Wc,
    float* __restrict__ skipm, unsigned* __restrict__ EF, float2* __restrict__ C12,
    __hip_bfloat16* __restrict__ xb_) {
    __shared__ float wcs[FIN][80];
    __shared__ float xs[16][FIN + 5];
    const int n0 = blockIdx.x * 16;
    const int tid = threadIdx.x;
    for (int i = tid; i < FIN * 80 / 4; i += 256)
        ((float4*)&wcs[0][0])[i] = ((const float4*)Wc)[i];
    const float4* xsrc = (const float4*)(x + (size_t)n0 * FIN);
    for (int i = tid; i < 16 * FIN / 4; i += 256) {
        int r = i >> 5, c4 = i & 31;
        *(float4*)&xs[r][c4 * 4] = xsrc[i];
    }
    __syncthreads();
    const int r = tid & 15;
    const int g = tid >> 4;
    float acc[4];
    float sa = 0.f;
#pragma unroll
    for (int j = 0; j < 4; ++j) acc[j] = 0.f;
#pragma unroll 4
    for (int i = 0; i < FIN; ++i) {
        float xv = xs[r][i];
        float4 p = *(float4*)&wcs[i][16 + g * 4];
        float qv = wcs[i][g];
        acc[0] += xv * p.x; acc[1] += xv * p.y; acc[2] += xv * p.z; acc[3] += xv * p.w;
        sa += xv * qv;
    }
    int n = n0 + r;
#pragma unroll
    for (int j = 0; j < 4; ++j) skipm[(size_t)n * FOUT + g * 4 + j] = acc[j];
    if (g < 8) {
        C12[g * NN + n] = make_float2(expf(sa), expf(0.2f * sa));
    } else {
        __hip_bfloat16 e0 = __float2bfloat16(expf(sa));
        __hip_bfloat16 f0 = __float2bfloat16(expf(0.2f * sa));
        EF[(g - 8) * NN + n] = ((unsigned)*(unsigned short*)&f0 << 16) | (unsigned)*(unsigned short*)&e0;
    }
    {
        int row = tid >> 4, col0 = (tid & 15) * 8;
        const float* src = &xs[row][col0];
        bf16x8 b0;
#pragma unroll
        for (int j = 0; j < 8; ++j) b0[j] = (__bf16)src[j];
        *(bf16x8*)((__bf16*)xb_ + (size_t)(n0 + row) * FIN + col0) = b0;
    }
}

// ---------------- K2: Vt[h][f][n] = proj[h]^T @ x^T via bf16 MFMA (R12, unchanged)
__global__ __launch_bounds__(256) void vt_kernel(
    const float* __restrict__ proj, const __hip_bfloat16* __restrict__ xb_,
    __hip_bfloat16* __restrict__ Vt_) {
    __shared__ __bf16 pT[FOUT][FIN + 8];
    const int tid = threadIdx.x;
    const int h = blockIdx.x >> 6;
    const int ng = blockIdx.x & 63;
    const __bf16* xb = (const __bf16*)xb_;
    __bf16* Vt = (__bf16*)Vt_;
    for (int idx = tid; idx < FIN * FOUT; idx += 256) {
        int i = idx >> 6, f = idx & 63;
        pT[f][i] = (__bf16)proj[(size_t)h * FIN * FOUT + idx];
    }
    __syncthreads();
    const int wave = tid >> 6, lane = tid & 63, q = lane >> 4, li = lane & 15;
    const int nb = ng * 64 + wave * 16;
    f32x4 acc[4];
#pragma unroll
    for (int n = 0; n < 4; ++n) acc[n] = (f32x4){0.f, 0.f, 0.f, 0.f};
#pragma unroll
    for (int kt = 0; kt < 4; ++kt) {
        bf16x8 bfrag = *(const bf16x8*)(xb + (size_t)(nb + li) * FIN + kt * 32 + q * 8);
#pragma unroll
        for (int ft = 0; ft < 4; ++ft) {
            bf16x8 afrag = *(const bf16x8*)&pT[ft * 16 + li][kt * 32 + q * 8];
            acc[ft] = __builtin_amdgcn_mfma_f32_16x16x32_bf16(afrag, bfrag, acc[ft], 0, 0, 0);
        }
    }
#pragma unroll
    for (int ft = 0; ft < 4; ++ft)
#pragma unroll
        for (int reg = 0; reg < 4; ++reg)
            Vt[((size_t)h * FOUT + ft * 16 + q * 4 + reg) * NN + nb + li] = (__bf16)acc[ft][reg];
}

// ---------------- K3: attention (R12, unchanged): head-per-wave, wave-private
// LDS-DMA double buffer, MFMA row-sums. grid = 128 qt x 4 ks x 2 hb = 1024 x 256.
__attribute__((amdgpu_waves_per_eu(4)))
__global__ __launch_bounds__(256) void attn_kernel(
    const u64* __restrict__ maskbits, const __hip_bfloat16* __restrict__ Vt_,
    const unsigned* __restrict__ EFg, const float2* __restrict__ C12g,
    __hip_bfloat16* __restrict__ accP, float* __restrict__ rsP) {
    __shared__ u64 maskS[QT][17];         // 4.4 KB
    __shared__ char vA[4][4096];          // 16 KB: per-wave buffer A
    __shared__ char vB[4][4096];          // 16 KB: per-wave buffer B
    const int tid = threadIdx.x;
    const int w = tid >> 6;
    const int lane = tid & 63, q = lane >> 4, li = lane & 15;
    const int qt = blockIdx.x >> 3, ks = (blockIdx.x >> 1) & 3, hb = blockIdx.x & 1;
    const int h = hb * 4 + w;
    const int row0 = qt * QT;
    const int kb0 = ks * 1024;

    const int r_ = lane >> 2;
    const int sg = ((lane & 3) - (r_ >> 1)) & 3;
    const size_t laneoff = (size_t)r_ * NN + sg * 8;            // bf16 units
    const int rdoff = li * 64 + ((q + (li >> 1)) & 3) * 16;     // bytes

    const __bf16* vb = (const __bf16*)Vt_ + (size_t)h * (FOUT * NN) + kb0;
    const unsigned* efb = EFg + (size_t)h * NN + kb0;

#define DMA_TILE(DST, KT) do {                                                     \
    _Pragma("unroll")                                                              \
    for (int c = 0; c < 4; ++c) {                                                  \
        const __bf16* g_ = vb + (size_t)c * (16 * NN) + (KT) * 32 + laneoff;       \
        __builtin_amdgcn_global_load_lds(                                          \
            (const __attribute__((address_space(1))) void*)g_,                     \
            (__attribute__((address_space(3))) void*)&DST[w][c * 1024], 16, 0, 0); \
    }                                                                              \
} while (0)

    DMA_TILE(vA, 0);
    {   // stage 32 rows x 16 mask words (512 words, 2 per thread)
        int i0 = tid, i1 = tid + 256;
        maskS[i0 >> 4][i0 & 15] = maskbits[(size_t)(row0 + (i0 >> 4)) * 64 + ks * 16 + (i0 & 15)];
        maskS[i1 >> 4][i1 & 15] = maskbits[(size_t)(row0 + (i1 >> 4)) * 64 + ks * 16 + (i1 & 15)];
    }
    __syncthreads();                      // also drains DMA(0)

    float C1[2], C2[2];
#pragma unroll
    for (int rt = 0; rt < 2; ++rt) {
        float2 c = C12g[(size_t)h * NN + row0 + rt * 16 + li];
        C1[rt] = c.x; C2[rt] = c.y;
    }
    bf16x8 ones;
#pragma unroll
    for (int j = 0; j < 8; ++j) ones[j] = (__bf16)1.0f;

    f32x4 acc[2][4];
    f32x4 rsacc[2];
#pragma unroll
    for (int rt = 0; rt < 2; ++rt) {
#pragma unroll
        for (int n = 0; n < 4; ++n) acc[rt][n] = (f32x4){0.f, 0.f, 0.f, 0.f};
        rsacc[rt] = (f32x4){0.f, 0.f, 0.f, 0.f};
    }

#define CHUNK_BODY(SRC, DSTN, KT) do {                                                        \
    const unsigned* ep_ = efb + (KT) * 32 + q * 8;                                            \
    uint4 ea_ = *(const uint4*)ep_;                                                           \
    uint4 eb_ = *(const uint4*)(ep_ + 4);                                                     \
    asm volatile("" ::: "memory");             /* pin EF loads before the DMA */              \
    DMA_TILE(DSTN, ((KT) + 1) & 31);                                                          \
    asm volatile("s_waitcnt vmcnt(4)" ::: "memory");                                          \
    bf16x8 vf_[4];                                                                            \
    _Pragma("unroll")                                                                         \
    for (int n = 0; n < 4; ++n)                                                               \
        vf_[n] = *(const bf16x8*)&SRC[w][n * 1024 + rdoff];                                   \
    unsigned ew_[8] = {ea_.x, ea_.y, ea_.z, ea_.w, eb_.x, eb_.y, eb_.z, eb_.w};               \
    _Pragma("unroll")                                                                         \
    for (int rt = 0; rt < 2; ++rt) {                                                          \
        u64 mw_ = maskS[rt * 16 + li][(KT) >> 1];                                             \
        unsigned mm_ = (unsigned)(mw_ >> (((KT) & 1) * 32 + q * 8)) & 0xffu;                  \
        bf16x8 pf_;                                                                           \
        _Pragma("unroll")                                                                     \
        for (int j = 0; j < 8; ++j) {                                                         \
            unsigned e_ = ew_[j];                                                             \
            float E_ = __uint_as_float(e_ << 16);                                             \
            float F_ = __uint_as_float(e_ & 0xffff0000u);                                     \
            float pv_ = fmaxf(C1[rt] * E_, C2[rt] * F_);                                      \
            pv_ = ((mm_ >> j) & 1u) ? pv_ : 0.f;                                              \
            pf_[j] = (__bf16)pv_;                                                             \
        }                                                                                     \
        rsacc[rt] = __builtin_amdgcn_mfma_f32_16x16x32_bf16(pf_, ones, rsacc[rt], 0, 0, 0);   \
        _Pragma("unroll")                                                                     \
        for (int n = 0; n < 4; ++n)                                                           \
            acc[rt][n] = __builtin_amdgcn_mfma_f32_16x16x32_bf16(pf_, vf_[n], acc[rt][n],     \
                                                                 0, 0, 0);                    \
    }                                                                                         \
} while (0)

#pragma unroll 1
    for (int kt = 0; kt < 32; kt += 2) {
        CHUNK_BODY(vA, vB, kt);
        CHUNK_BODY(vB, vA, kt + 1);
    }
#undef CHUNK_BODY
#undef DMA_TILE

#pragma unroll
    for (int rt = 0; rt < 2; ++rt) {
        if (li == 0) {
#pragma unroll
            for (int reg = 0; reg < 4; ++reg)
                rsP[(size_t)(ks * NH + h) * NN + row0 + rt * 16 + q * 4 + reg] = rsacc[rt][reg];
        }
        __hip_bfloat16* ap = accP + ((size_t)(ks * NH + h) * NN + row0 + rt * 16) * 64;
#pragma unroll
        for (int n = 0; n < 4; ++n)
#pragma unroll
            for (int reg = 0; reg < 4; ++reg)
                ap[(q * 4 + reg) * 64 + n * 16 + li] = __float2bfloat16(acc[rt][n][reg]);
    }
}

// ---------------- K4: combine k-split partials + mean heads + skip + LeakyReLU
__global__ __launch_bounds__(256) void combine_kernel(
    const __hip_bfloat16* __restrict__ accP, const float* __restrict__ rsP,
    float* __restrict__ out) {
    int idx = blockIdx.x * 256 + threadIdx.x;      // 262144
    int row = idx >> 6, f = idx & 63;
    float s = 0.f;
#pragma unroll 1
    for (int h = 0; h < NH; ++h) {
        float a = 0.f, r = 0.f;
#pragma unroll
        for (int k = 0; k < KS; ++k) {
            a += __bfloat162float(accP[((size_t)(k * NH + h) * NN + row) * 64 + f]);
            r += rsP[(size_t)(k * NH + h) * NN + row];
        }
        s += a / r;
    }
    float v = s * 0.125f + out[idx];               // out currently holds skipm
    out[idx] = fmaxf(v, 0.2f * v);
}

extern "C" void kernel_launch(void* const* d_in, const int* in_sizes, int n_in,
                              void* d_out, int out_size, void* d_ws, size_t ws_size,
                              hipStream_t stream) {
    (void)in_sizes; (void)n_in; (void)out_size; (void)ws_size;
    const float* x         = (const float*)d_in[0];   // [4096,128]
    const float* topology  = (const float*)d_in[1];   // [4096,4096]
    const float* proj      = (const float*)d_in[2];   // [8,128,64]
    const float* score_src = (const float*)d_in[3];   // [8,64]
    const float* score_dst = (const float*)d_in[4];   // [8,64]
    const float* skip_w    = (const float*)d_in[5];   // [512,128]
    float* out = (float*)d_out;                       // [4096,64]

    char* ws = (char*)d_ws;
    __hip_bfloat16* xb = (__hip_bfloat16*)ws;                 // 1 MB
    __hip_bfloat16* Vt = (__hip_bfloat16*)(ws + 1048576);     // 4 MB
    unsigned* EF  = (unsigned*)(ws + 5242880);                // 128 KB
    float2* C12   = (float2*)(ws + 5373952);                  // 256 KB
    float* Wc     = (float*)(ws + 5636096);                   // 40 KB
    u64* maskbits = (u64*)(ws + 5677056);                     // 2 MB
    float* rsP    = (float*)(ws + 7774208);                   // 512 KB
    __hip_bfloat16* accP = (__hip_bfloat16*)(ws + 8298496);   // 16 MB (end ~24.3 MB)
    float* skipm = out;   // skip GEMM lives in d_out; combine consumes & overwrites

    maskwc_kernel<<<2088, 256, 0, stream>>>(topology, maskbits, proj, score_src,
                                            score_dst, skip_w, Wc);
    scores_kernel<<<256, 256, 0, stream>>>(x, Wc, skipm, EF, C12, xb);
    vt_kernel<<<512, 256, 0, stream>>>(proj, xb, Vt);
    attn_kernel<<<1024, 256, 0, stream>>>(maskbits, Vt, EF, C12, accP, rsP);
    combine_kernel<<<1024, 256, 0, stream>>>(accP, rsP, out);
}